// Round 16
// baseline (17476.627 us; speedup 1.0000x reference)
//
#include <hip/hip_runtime.h>
#include <stdint.h>

// F=1024, H=512, S=512, B=32, T=128
// Round-15 base. Changes:
//  1) Decoder 512 -> 1024 threads via 2-way k-split (gpartK[2][2][32][17],
//     fixed combine order); staging = 1 float4/thread/chunk, 2-deep ping-pong.
//  2) Encoder: next-step feats chunk-0 prefetch issued before the barrier.

#define NWG 256

__device__ __forceinline__ float sigm(float x) { return 1.0f / (1.0f + __expf(-x)); }
__device__ __forceinline__ float tanhx(float x) {
  float e = __expf(2.0f * x);
  return 1.0f - 2.0f / (e + 1.0f);
}

__device__ __forceinline__ float ldc(const float* p) {
  return __hip_atomic_load(p, __ATOMIC_RELAXED, __HIP_MEMORY_SCOPE_AGENT);
}
__device__ __forceinline__ float2 ldc2(const float* p) {
  double d = __hip_atomic_load((const double*)p, __ATOMIC_RELAXED, __HIP_MEMORY_SCOPE_AGENT);
  return __builtin_bit_cast(float2, d);
}
__device__ __forceinline__ void stc(float* p, float v) {
  __hip_atomic_store(p, v, __ATOMIC_RELAXED, __HIP_MEMORY_SCOPE_AGENT);
}
__device__ __forceinline__ int ldci(const int* p) {
  return __hip_atomic_load(p, __ATOMIC_RELAXED, __HIP_MEMORY_SCOPE_AGENT);
}
__device__ __forceinline__ void stci(int* p, int v) {
  __hip_atomic_store(p, v, __ATOMIC_RELAXED, __HIP_MEMORY_SCOPE_AGENT);
}

__device__ __forceinline__ void tree_barrier(int* bar, int w, int epoch) {
  __syncthreads();
  if (threadIdx.x == 0) {
    const int g = w >> 3;
    int* gc = bar + g * 64;
    int* rc = bar + 2048;
    int* gf = bar + 2112 + g * 64;
    int old = __hip_atomic_fetch_add(gc, 1, __ATOMIC_RELAXED, __HIP_MEMORY_SCOPE_AGENT);
    if (old == epoch * 8 - 1) {
      __hip_atomic_fetch_add(rc, 1, __ATOMIC_RELAXED, __HIP_MEMORY_SCOPE_AGENT);
      while (__hip_atomic_load(rc, __ATOMIC_RELAXED, __HIP_MEMORY_SCOPE_AGENT) < epoch * 32)
        __builtin_amdgcn_s_sleep(2);
      __hip_atomic_store(gf, epoch, __ATOMIC_RELAXED, __HIP_MEMORY_SCOPE_AGENT);
    } else {
      while (__hip_atomic_load(gf, __ATOMIC_RELAXED, __HIP_MEMORY_SCOPE_AGENT) < epoch)
        __builtin_amdgcn_s_sleep(2);
    }
  }
  __syncthreads();
}

// ---------------------------------------------------------------------------
// Encoder: 256 WGs x 1024 thr (round-15 structure) + next-step feats prefetch.
// ---------------------------------------------------------------------------
__global__ __launch_bounds__(1024) void encoder_kernel(
    const float* __restrict__ feats,
    const float* __restrict__ Wih_f, const float* __restrict__ Whh_f,
    const float* __restrict__ bih_f, const float* __restrict__ bhh_f,
    const float* __restrict__ Wih_b, const float* __restrict__ Whh_b,
    const float* __restrict__ bih_b, const float* __restrict__ bhh_b,
    const float* __restrict__ W_enc, const float* __restrict__ b_enc,
    float* __restrict__ enc_proj, float* __restrict__ henc,
    float* __restrict__ cfin, int* __restrict__ bar)
{
  extern __shared__ __align__(16) float dyn[];
  float* wih_l = dyn;            // 16 x 1028
  float* whh_l = dyn + 16448;    // 16 x 516
  __shared__ float hch[32 * 260];
  __shared__ float wenc[4 * 516];
  __shared__ float gpartK[2][32][17];
  __shared__ float projp[2][2][128];
  __shared__ float bias_s[16];
  __shared__ float benc_s[4];

  const int w = blockIdx.x;
  const int dir = (w >= 128) ? 1 : 0;
  const int wl = w & 127;
  const int col0 = wl * 4;
  const int t = threadIdx.x;
  const int kk2 = t >> 9;
  const int u = t & 511;
  const int g = u >> 7;
  const int tt = u & 127;
  const int b = tt >> 2;
  const int ci = tt & 3;
  const int col = col0 + ci;
  const int p0b = t >> 6,          p0q = t & 63;
  const int p1b = (t + 1024) >> 6, p1q = (t + 1024) & 63;

  const float* Wih = dir ? Wih_b : Wih_f;
  const float* Whh = dir ? Whh_b : Whh_f;
  const float* bih = dir ? bih_b : bih_f;
  const float* bhh = dir ? bhh_b : bhh_f;

  for (int i = t; i < 16 * 256; i += 1024) {
    int r = i >> 8, q = i & 255;
    int gg = r >> 2, cj = r & 3;
    *(float4*)(wih_l + r * 1028 + q * 4) =
        *(const float4*)(Wih + (size_t)(gg * 512 + col0 + cj) * 1024 + q * 4);
  }
  for (int i = t; i < 16 * 128; i += 1024) {
    int r = i >> 7, q = i & 127;
    int gg = r >> 2, cj = r & 3;
    *(float4*)(whh_l + r * 516 + q * 4) =
        *(const float4*)(Whh + (size_t)(gg * 512 + col0 + cj) * 512 + q * 4);
  }
  for (int i = t; i < 4 * 128; i += 1024) {
    int jl = i >> 7, q = i & 127;
    *(float4*)(wenc + jl * 516 + q * 4) =
        *(const float4*)(W_enc + (size_t)(col0 + jl) * 1024 + dir * 512 + q * 4);
  }
  if (t < 16) {
    int gg = t >> 2, cj = t & 3;
    bias_s[t] = bih[gg * 512 + col0 + cj] + bhh[gg * 512 + col0 + cj];
  }
  if (t < 4) benc_s[t] = b_enc[col0 + t];
  float c_reg = 0.0f;
  __syncthreads();

  const float* wx = wih_l + (g * 4 + ci) * 1028;
  const float* wh = whh_l + (g * 4 + ci) * 516;
  const float* wpe = wenc + ci * 516;
  const int kq = kk2 * 2 + g;

  // prefetch feats chunk 0 for it=0
  const int s0_ = dir ? 511 : 0;
  float4 fx0 = *(const float4*)(feats + ((size_t)s0_ * 32) * 1024 + p0b * 1024 + p0q * 4);
  float4 fx1 = *(const float4*)(feats + ((size_t)s0_ * 32) * 1024 + p1b * 1024 + p1q * 4);

  for (int it = 0; it < 512; ++it) {
    const int s = dir ? (511 - it) : it;
    float acc = 0.0f, projacc = 0.0f;
    const float* fsrc = feats + ((size_t)s * 32) * 1024;
    const float* hsrc = henc + dir * 32768 + ((it - 1) & 1) * 16384;

    float2 h00a, h00b, h01a, h01b;
    float2 h10a, h10b, h11a, h11b;
    if (it > 0) {
      const float* sp;
      sp = hsrc + p0b * 512 + p0q * 4;       h00a = ldc2(sp); h00b = ldc2(sp + 2);
      sp = hsrc + p1b * 512 + p1q * 4;       h01a = ldc2(sp); h01b = ldc2(sp + 2);
      sp = hsrc + p0b * 512 + 256 + p0q * 4; h10a = ldc2(sp); h10b = ldc2(sp + 2);
      sp = hsrc + p1b * 512 + 256 + p1q * 4; h11a = ldc2(sp); h11b = ldc2(sp + 2);
    }

    // ---- x phase: 4 chunks of [32][256]; chunk 0 from prefetched fx ----
    {
      float4 xv0 = fx0;
      float4 xv1 = fx1;
      for (int ch = 0; ch < 4; ++ch) {
        *(float4*)(hch + p0b * 260 + p0q * 4) = xv0;
        *(float4*)(hch + p1b * 260 + p1q * 4) = xv1;
        __syncthreads();
        if (ch < 3) {
          xv0 = *(const float4*)(fsrc + p0b * 1024 + (ch + 1) * 256 + p0q * 4);
          xv1 = *(const float4*)(fsrc + p1b * 1024 + (ch + 1) * 256 + p1q * 4);
        }
        const float* hrow = hch + b * 260 + kk2 * 128;
        const float* pw = wx + ch * 256 + kk2 * 128;
#pragma unroll 8
        for (int q = 0; q < 32; ++q) {
          float4 f4 = *(const float4*)(hrow + q * 4);
          float4 a4 = *(const float4*)(pw + q * 4);
          acc += f4.x * a4.x + f4.y * a4.y + f4.z * a4.z + f4.w * a4.w;
        }
        __syncthreads();
      }
    }

    // ---- h phase ----
    if (it > 0) {
      *(float4*)(hch + p0b * 260 + p0q * 4) = make_float4(h00a.x, h00a.y, h00b.x, h00b.y);
      *(float4*)(hch + p1b * 260 + p1q * 4) = make_float4(h01a.x, h01a.y, h01b.x, h01b.y);
      __syncthreads();
      {
        const float* hrow = hch + b * 260 + kk2 * 128;
        const float* pw = wh + kk2 * 128;
#pragma unroll 8
        for (int q = 0; q < 32; ++q) {
          float4 h4 = *(const float4*)(hrow + q * 4);
          float4 a4 = *(const float4*)(pw + q * 4);
          acc += h4.x * a4.x + h4.y * a4.y + h4.z * a4.z + h4.w * a4.w;
        }
        if (g < 2) {
          const float* hp = hch + b * 260 + kq * 64;
          const float* wp = wpe + kq * 64;
#pragma unroll 4
          for (int kk = 0; kk < 16; ++kk) {
            float4 h4 = *(const float4*)(hp + kk * 4);
            float4 w4 = *(const float4*)(wp + kk * 4);
            projacc += h4.x * w4.x + h4.y * w4.y + h4.z * w4.z + h4.w * w4.w;
          }
        }
      }
      __syncthreads();
      *(float4*)(hch + p0b * 260 + p0q * 4) = make_float4(h10a.x, h10a.y, h10b.x, h10b.y);
      *(float4*)(hch + p1b * 260 + p1q * 4) = make_float4(h11a.x, h11a.y, h11b.x, h11b.y);
      __syncthreads();
      {
        const float* hrow = hch + b * 260 + kk2 * 128;
        const float* pw = wh + 256 + kk2 * 128;
#pragma unroll 8
        for (int q = 0; q < 32; ++q) {
          float4 h4 = *(const float4*)(hrow + q * 4);
          float4 a4 = *(const float4*)(pw + q * 4);
          acc += h4.x * a4.x + h4.y * a4.y + h4.z * a4.z + h4.w * a4.w;
        }
        if (g < 2) {
          const float* hp = hch + b * 260 + kq * 64;
          const float* wp = wpe + 256 + kq * 64;
#pragma unroll 4
          for (int kk = 0; kk < 16; ++kk) {
            float4 h4 = *(const float4*)(hp + kk * 4);
            float4 w4 = *(const float4*)(wp + kk * 4);
            projacc += h4.x * w4.x + h4.y * w4.y + h4.z * w4.z + h4.w * w4.w;
          }
        }
      }
      __syncthreads();
    }

    gpartK[kk2][b][g * 4 + ci] = acc;
    if (g < 2) projp[kk2][g][tt] = projacc;
    __syncthreads();
    if (t < 128) {
      float gi = gpartK[0][b][ci + 0] + gpartK[1][b][ci + 0] + bias_s[ci + 0];
      float gf = gpartK[0][b][ci + 4] + gpartK[1][b][ci + 4] + bias_s[ci + 4];
      float gg = gpartK[0][b][ci + 8] + gpartK[1][b][ci + 8] + bias_s[ci + 8];
      float go = gpartK[0][b][ci + 12] + gpartK[1][b][ci + 12] + bias_s[ci + 12];
      float cn = sigm(gf) * c_reg + sigm(gi) * tanhx(gg);
      c_reg = cn;
      stc(henc + dir * 32768 + (it & 1) * 16384 + b * 512 + col,
          sigm(go) * tanhx(cn));
    } else if (kk2 == 0 && g == 1 && it > 0) {
      const int sp = dir ? (512 - it) : (it - 1);
      const float p = projp[0][0][tt] + projp[0][1][tt] +
                      projp[1][0][tt] + projp[1][1][tt];
      float* addr = enc_proj + ((size_t)sp * 32 + b) * 512 + col;
      if (it - 1 <= 255) {
        stc(addr, p + benc_s[ci]);
      } else {
        stc(addr, ldc(addr) + p);
      }
    }
    // prefetch next step's feats chunk 0 (hidden under the barrier)
    {
      const int sn = (it < 511) ? (dir ? (510 - it) : (it + 1)) : s;
      const float* fn = feats + ((size_t)sn * 32) * 1024;
      fx0 = *(const float4*)(fn + p0b * 1024 + p0q * 4);
      fx1 = *(const float4*)(fn + p1b * 1024 + p1q * 4);
    }
    tree_barrier(bar, w, it + 1);
  }

  // post-loop: proj for e=511 (second arriver), and cfin
  {
    const float* hsrc = henc + dir * 32768 + 16384;
    float projacc = 0.0f;
    for (int ch = 0; ch < 2; ++ch) {
      for (int i = t; i < 2048; i += 1024) {
        int bb = i >> 6, qf = i & 63;
        const float* sp = hsrc + bb * 512 + ch * 256 + qf * 4;
        float2 f0 = ldc2(sp);
        float2 f1 = ldc2(sp + 2);
        *(float4*)(hch + bb * 260 + qf * 4) = make_float4(f0.x, f0.y, f1.x, f1.y);
      }
      __syncthreads();
      if (g < 2) {
        const float* hp = hch + b * 260 + kq * 64;
        const float* wp = wpe + ch * 256 + kq * 64;
#pragma unroll 4
        for (int kk = 0; kk < 16; ++kk) {
          float4 h4 = *(const float4*)(hp + kk * 4);
          float4 w4 = *(const float4*)(wp + kk * 4);
          projacc += h4.x * w4.x + h4.y * w4.y + h4.z * w4.z + h4.w * w4.w;
        }
      }
      __syncthreads();
    }
    if (g < 2) projp[kk2][g][tt] = projacc;
    __syncthreads();
    if (kk2 == 0 && g == 1) {
      const int sp = dir ? 0 : 511;
      float* addr = enc_proj + ((size_t)sp * 32 + b) * 512 + col;
      stc(addr, ldc(addr) + (projp[0][0][tt] + projp[0][1][tt] +
                             projp[1][0][tt] + projp[1][1][tt]));
    }
    if (t < 128) cfin[dir * 16384 + b * 512 + col] = c_reg;
  }
}

// ---------------------------------------------------------------------------
// Decoder: 256 WGs x 1024 thr, 2-way k-split. 3 barriers/step, 2-deep
// ping-pong staging (1 float4/thread/chunk).
// ---------------------------------------------------------------------------
__global__ __launch_bounds__(1024) void decoder_kernel(
    const float* __restrict__ feats,
    const float* __restrict__ Wih_d, const float* __restrict__ Whh_d,
    const float* __restrict__ bih_d, const float* __restrict__ bhh_d,
    const float* __restrict__ W_dec, const float* __restrict__ b_dec,
    const float* __restrict__ W_v, const float* __restrict__ b_v,
    const float* __restrict__ enc_proj, const float* __restrict__ henc,
    const float* __restrict__ cfin,
    float* __restrict__ hbuf, float* __restrict__ dproj,
    float* __restrict__ pval, int* __restrict__ pidx,
    int* __restrict__ bar, float* __restrict__ out)
{
  extern __shared__ __align__(16) float dyn[];
  float* whh_l = dyn;            // 16 x 1028
  float* wih_l = dyn + 16448;    // 16 x 1028
  __shared__ float hch[32 * 132];
  __shared__ float gpartK[2][2][32][17];
  __shared__ float c_lds[32][4];
  __shared__ float bias_s[16];
  __shared__ float svals[64];
  __shared__ int ib_lds[32];
  float* dpl = hch + 1088;   // [8][68] dproj slice for phase C (alias)

  const int w = blockIdx.x;
  const int t = threadIdx.x;
  const int kk2A = t >> 9;           // k-half within each 128-chunk
  const int u = t & 511;
  const int q4 = u >> 7;             // {Whh,Wih} x gate-pair
  const int tt = u & 127;
  const int b = tt >> 2;
  const int ci = tt & 3;
  const int col0 = w * 4;
  const int col = col0 + ci;
  const int bbS = t >> 5, qqS = t & 31;   // staging: 1 float4/thread
  const int bb_c = w >> 3;
  const int qq_ = w & 7;
  const int ccB = t >> 9;            // phase B col
  const int bB = (t >> 4) & 31;      // phase B batch
  const int k16 = t & 15;            // phase B k-slice

  for (int i = t; i < 16 * 256; i += 1024) {
    int r = i >> 8, q = i & 255;
    int gg = r >> 2, cj = r & 3;
    *(float4*)(whh_l + r * 1028 + q * 4) =
        *(const float4*)(Whh_d + (size_t)(gg * 1024 + col0 + cj) * 1024 + q * 4);
    *(float4*)(wih_l + r * 1028 + q * 4) =
        *(const float4*)(Wih_d + (size_t)(gg * 1024 + col0 + cj) * 1024 + q * 4);
  }
  if (t < 16) {
    int gg = t >> 2, cj = t & 3;
    bias_s[t] = bih_d[gg * 1024 + col0 + cj] + bhh_d[gg * 1024 + col0 + cj];
  }
  if (t < 128) {
    int flat = b * 1024 + col;
    int d = flat >> 14, sb = (flat >> 9) & 31, sh = flat & 511;
    float h0, c0;
    if (d == 0) {
      h0 = henc[16384 + sb * 512 + sh];
      c0 = cfin[sb * 512 + sh];
    } else {
      h0 = henc[32768 + 16384 + sb * 512 + sh];
      c0 = cfin[16384 + sb * 512 + sh];
    }
    stc(hbuf + b * 1024 + col, h0);
    c_lds[b][ci] = c0;
  }
  int bars = 1;
  tree_barrier(bar, w, bars);

  const float* wbase = (q4 < 2) ? whh_l : wih_l;
  const int g0 = (q4 & 1) * 2;
  const float* wr0 = wbase + (size_t)((g0 + 0) * 4 + ci) * 1028 + kk2A * 64;
  const float* wr1 = wbase + (size_t)((g0 + 1) * 4 + ci) * 1028 + kk2A * 64;

  for (int ts = 0; ts < 128; ++ts) {
    const float* hprev = hbuf + (ts & 1) * 32768;
    float* hnext = hbuf + ((ts + 1) & 1) * 32768;

    // ---- phase A: gates GEMM (2-deep staged) + cell; ib fold ----
    float a0 = 0.f, a1 = 0.f;
    const float* xrow = nullptr;
    {
      float2 pA0 = ldc2(hprev + bbS * 1024 + qqS * 4);
      float2 pA1 = ldc2(hprev + bbS * 1024 + qqS * 4 + 2);
      float2 pB0 = ldc2(hprev + bbS * 1024 + 128 + qqS * 4);
      float2 pB1 = ldc2(hprev + bbS * 1024 + 128 + qqS * 4 + 2);
      if (t < 32) {
        int ib = 0;
        if (ts > 0) {
          float v = ldc(pval + t * 8 + 0);
          int si = ldci(pidx + t * 8 + 0);
#pragma unroll
          for (int j = 1; j < 8; ++j) {
            float ov = ldc(pval + t * 8 + j);
            int os = ldci(pidx + t * 8 + j);
            if (ov > v || (ov == v && os < si)) { v = ov; si = os; }
          }
          ib = si;
        }
        ib_lds[t] = ib;
      }
      for (int ch = 0; ch < 8; ++ch) {
        if (ch & 1) {
          *(float4*)(hch + bbS * 132 + qqS * 4) = make_float4(pB0.x, pB0.y, pB1.x, pB1.y);
        } else {
          *(float4*)(hch + bbS * 132 + qqS * 4) = make_float4(pA0.x, pA0.y, pA1.x, pA1.y);
        }
        __syncthreads();
        if (ch == 0 && q4 >= 2) {
          int ib = ib_lds[b];
          xrow = feats + ((size_t)ib * 32 + b) * 1024;
        }
        if (ch < 6) {
          const int cn = (ch + 2) * 128;
          if (ch & 1) {
            pB0 = ldc2(hprev + bbS * 1024 + cn + qqS * 4);
            pB1 = ldc2(hprev + bbS * 1024 + cn + qqS * 4 + 2);
          } else {
            pA0 = ldc2(hprev + bbS * 1024 + cn + qqS * 4);
            pA1 = ldc2(hprev + bbS * 1024 + cn + qqS * 4 + 2);
          }
        }
        const float* src = (q4 < 2) ? (hch + b * 132 + kk2A * 64)
                                    : (xrow + ch * 128 + kk2A * 64);
        const float* p0 = wr0 + ch * 128;
        const float* p1 = wr1 + ch * 128;
#pragma unroll
        for (int qq = 0; qq < 16; ++qq) {
          float4 h4 = *(const float4*)(src + qq * 4);
          float4 u0 = *(const float4*)(p0 + qq * 4);
          float4 u1 = *(const float4*)(p1 + qq * 4);
          a0 += h4.x * u0.x + h4.y * u0.y + h4.z * u0.z + h4.w * u0.w;
          a1 += h4.x * u1.x + h4.y * u1.y + h4.z * u1.z + h4.w * u1.w;
        }
        __syncthreads();
      }
    }
    gpartK[kk2A][q4 >> 1][b][ci + (g0 + 0) * 4] = a0;
    gpartK[kk2A][q4 >> 1][b][ci + (g0 + 1) * 4] = a1;
    __syncthreads();
    if (t < 128) {
      float gi = (gpartK[0][0][b][ci + 0] + gpartK[0][1][b][ci + 0]) +
                 (gpartK[1][0][b][ci + 0] + gpartK[1][1][b][ci + 0]) + bias_s[ci + 0];
      float gf = (gpartK[0][0][b][ci + 4] + gpartK[0][1][b][ci + 4]) +
                 (gpartK[1][0][b][ci + 4] + gpartK[1][1][b][ci + 4]) + bias_s[ci + 4];
      float gg = (gpartK[0][0][b][ci + 8] + gpartK[0][1][b][ci + 8]) +
                 (gpartK[1][0][b][ci + 8] + gpartK[1][1][b][ci + 8]) + bias_s[ci + 8];
      float go = (gpartK[0][0][b][ci + 12] + gpartK[0][1][b][ci + 12]) +
                 (gpartK[1][0][b][ci + 12] + gpartK[1][1][b][ci + 12]) + bias_s[ci + 12];
      float cn = sigm(gf) * c_lds[b][ci] + sigm(gi) * tanhx(gg);
      c_lds[b][ci] = cn;
      stc(hnext + b * 1024 + col, sigm(go) * tanhx(cn));
    }
    ++bars; tree_barrier(bar, w, bars);

    // ---- phase B: dproj cols {2w,2w+1}; 32 b x 16 k-slices ----
    {
      float dacc = 0.f;
      const float* wdrow = W_dec + (size_t)(2 * w + ccB) * 1024;
      float2 pA0 = ldc2(hnext + bbS * 1024 + qqS * 4);
      float2 pA1 = ldc2(hnext + bbS * 1024 + qqS * 4 + 2);
      float2 pB0 = ldc2(hnext + bbS * 1024 + 128 + qqS * 4);
      float2 pB1 = ldc2(hnext + bbS * 1024 + 128 + qqS * 4 + 2);
      for (int ch = 0; ch < 8; ++ch) {
        if (ch & 1) {
          *(float4*)(hch + bbS * 132 + qqS * 4) = make_float4(pB0.x, pB0.y, pB1.x, pB1.y);
        } else {
          *(float4*)(hch + bbS * 132 + qqS * 4) = make_float4(pA0.x, pA0.y, pA1.x, pA1.y);
        }
        __syncthreads();
        if (ch < 6) {
          const int cn = (ch + 2) * 128;
          if (ch & 1) {
            pB0 = ldc2(hnext + bbS * 1024 + cn + qqS * 4);
            pB1 = ldc2(hnext + bbS * 1024 + cn + qqS * 4 + 2);
          } else {
            pA0 = ldc2(hnext + bbS * 1024 + cn + qqS * 4);
            pA1 = ldc2(hnext + bbS * 1024 + cn + qqS * 4 + 2);
          }
        }
        const float* hl = hch + bB * 132 + k16 * 8;
        const float* wl = wdrow + ch * 128 + k16 * 8;
#pragma unroll
        for (int j = 0; j < 2; ++j) {
          float4 h4 = *(const float4*)(hl + j * 4);
          float4 w4 = *(const float4*)(wl + j * 4);
          dacc += h4.x * w4.x + h4.y * w4.y + h4.z * w4.z + h4.w * w4.w;
        }
        __syncthreads();
      }
      dacc += __shfl_xor(dacc, 1);
      dacc += __shfl_xor(dacc, 2);
      dacc += __shfl_xor(dacc, 4);
      dacc += __shfl_xor(dacc, 8);
      if (k16 == 0) stc(dproj + bB * 512 + 2 * w + ccB, dacc + b_dec[2 * w + ccB]);
    }
    ++bars; tree_barrier(bar, w, bars);

    // ---- phase C: scores, batch-major (WG: bb_c, s-block qq_) ----
    if (t < 256) {
      float2 v = ldc2(dproj + bb_c * 512 + 2 * t);
      int k = 2 * t;
      dpl[(k >> 6) * 68 + (k & 63) + 0] = v.x;
      dpl[(k >> 6) * 68 + (k & 63) + 1] = v.y;
    }
    __syncthreads();
    {
      const int sl = t >> 4, ks = t & 15;
      const int s = qq_ * 64 + sl;
      const float* ep = enc_proj + ((size_t)s * 32 + bb_c) * 512 + ks * 32;
      const float* dpp = dpl + (ks >> 1) * 68 + (ks & 1) * 32;
      const float* wvp = W_v + ks * 32;
      float sum = 0.f;
#pragma unroll
      for (int j = 0; j < 8; ++j) {
        float4 e4 = *(const float4*)(ep + j * 4);
        float4 d4 = *(const float4*)(dpp + j * 4);
        float4 v4 = *(const float4*)(wvp + j * 4);
        sum += tanhx(e4.x + d4.x) * v4.x;
        sum += tanhx(e4.y + d4.y) * v4.y;
        sum += tanhx(e4.z + d4.z) * v4.z;
        sum += tanhx(e4.w + d4.w) * v4.w;
      }
      sum += __shfl_xor(sum, 1);
      sum += __shfl_xor(sum, 2);
      sum += __shfl_xor(sum, 4);
      sum += __shfl_xor(sum, 8);
      if (ks == 0) {
        float sv = sum + b_v[0];
        out[((size_t)ts * 32 + bb_c) * 512 + s] = sv;
        svals[sl] = sv;
      }
    }
    __syncthreads();
    if (t < 64) {
      float v = svals[t];
      int si = qq_ * 64 + t;
#pragma unroll
      for (int m = 1; m < 64; m <<= 1) {
        float ov = __shfl_xor(v, m);
        int os = __shfl_xor(si, m);
        if (ov > v || (ov == v && os < si)) { v = ov; si = os; }
      }
      if (t == 0) {
        stc(pval + bb_c * 8 + qq_, v);
        stci(pidx + bb_c * 8 + qq_, si);
      }
    }
    ++bars; tree_barrier(bar, w, bars);
  }
}

// ---------------------------------------------------------------------------
extern "C" void kernel_launch(void* const* d_in, const int* in_sizes, int n_in,
                              void* d_out, int out_size, void* d_ws, size_t ws_size,
                              hipStream_t stream) {
  (void)in_sizes; (void)n_in; (void)out_size; (void)ws_size;
  const float* feats = (const float*)d_in[0];
  const float* Wih_f = (const float*)d_in[1];
  const float* Whh_f = (const float*)d_in[2];
  const float* bih_f = (const float*)d_in[3];
  const float* bhh_f = (const float*)d_in[4];
  const float* Wih_b = (const float*)d_in[5];
  const float* Whh_b = (const float*)d_in[6];
  const float* bih_b = (const float*)d_in[7];
  const float* bhh_b = (const float*)d_in[8];
  const float* Wih_d = (const float*)d_in[9];
  const float* Whh_d = (const float*)d_in[10];
  const float* bih_d = (const float*)d_in[11];
  const float* bhh_d = (const float*)d_in[12];
  const float* W_enc = (const float*)d_in[13];
  const float* b_enc = (const float*)d_in[14];
  const float* W_dec = (const float*)d_in[15];
  const float* b_dec = (const float*)d_in[16];
  const float* W_v   = (const float*)d_in[17];
  const float* b_v   = (const float*)d_in[18];
  float* out = (float*)d_out;

  int* ctrl = (int*)d_ws;
  int* bar_enc = ctrl;
  int* bar_dec = ctrl + 8192;
  float* base = (float*)d_ws + 16384;        // after 64 KiB ctrl block
  float* enc_proj = base;                    // 8,388,608
  float* henc     = enc_proj + 8388608;      //    65,536
  float* cfin     = henc + 65536;            //    32,768
  float* hbuf     = cfin + 32768;            //    65,536
  float* dproj    = hbuf + 65536;            //    16,384
  float* pval     = dproj + 16384;           //     8,192 (256 used)
  int*   pidx     = (int*)(pval + 8192);     //     8,192 (256 used)
  // total ~34.4 MB

  const int ENC_LDS = (16 * 1028 + 16 * 516) * 4;   //  98,816 B
  const int DEC_LDS = (2 * 16 * 1028) * 4;          // 131,584 B
  hipFuncSetAttribute((const void*)encoder_kernel,
                      hipFuncAttributeMaxDynamicSharedMemorySize, ENC_LDS);
  hipFuncSetAttribute((const void*)decoder_kernel,
                      hipFuncAttributeMaxDynamicSharedMemorySize, DEC_LDS);

  hipMemsetAsync(d_ws, 0, 65536, stream);

  {
    void* args[] = {(void*)&feats,
                    (void*)&Wih_f, (void*)&Whh_f, (void*)&bih_f, (void*)&bhh_f,
                    (void*)&Wih_b, (void*)&Whh_b, (void*)&bih_b, (void*)&bhh_b,
                    (void*)&W_enc, (void*)&b_enc,
                    (void*)&enc_proj, (void*)&henc, (void*)&cfin, (void*)&bar_enc};
    hipLaunchCooperativeKernel((const void*)encoder_kernel, dim3(NWG), dim3(1024),
                               args, ENC_LDS, stream);
  }
  {
    void* args[] = {(void*)&feats,
                    (void*)&Wih_d, (void*)&Whh_d, (void*)&bih_d, (void*)&bhh_d,
                    (void*)&W_dec, (void*)&b_dec, (void*)&W_v, (void*)&b_v,
                    (void*)&enc_proj, (void*)&henc, (void*)&cfin,
                    (void*)&hbuf, (void*)&dproj, (void*)&pval, (void*)&pidx,
                    (void*)&bar_dec, (void*)&out};
    hipLaunchCooperativeKernel((const void*)decoder_kernel, dim3(NWG), dim3(1024),
                               args, DEC_LDS, stream);
  }
}

// Round 17
// 16249.115 us; speedup vs baseline: 1.0755x; 1.0755x over previous
//
#include <hip/hip_runtime.h>
#include <stdint.h>

// F=1024, H=512, S=512, B=32, T=128
// Round-16 post-mortem: decoder 1024-thr split regressed -> revert decoder to
// round-14 512-thr version (measured 5.9 ms). Encoder: 4-way k-split x
// 2-batch register tiling (3 LDS reads per 8 FMAs, was 2 per 4); per-output
// k-order unchanged, combine widens to 4 fixed-order partials.

#define NWG 256

__device__ __forceinline__ float sigm(float x) { return 1.0f / (1.0f + __expf(-x)); }
__device__ __forceinline__ float tanhx(float x) {
  float e = __expf(2.0f * x);
  return 1.0f - 2.0f / (e + 1.0f);
}

__device__ __forceinline__ float ldc(const float* p) {
  return __hip_atomic_load(p, __ATOMIC_RELAXED, __HIP_MEMORY_SCOPE_AGENT);
}
__device__ __forceinline__ float2 ldc2(const float* p) {
  double d = __hip_atomic_load((const double*)p, __ATOMIC_RELAXED, __HIP_MEMORY_SCOPE_AGENT);
  return __builtin_bit_cast(float2, d);
}
__device__ __forceinline__ void stc(float* p, float v) {
  __hip_atomic_store(p, v, __ATOMIC_RELAXED, __HIP_MEMORY_SCOPE_AGENT);
}
__device__ __forceinline__ int ldci(const int* p) {
  return __hip_atomic_load(p, __ATOMIC_RELAXED, __HIP_MEMORY_SCOPE_AGENT);
}
__device__ __forceinline__ void stci(int* p, int v) {
  __hip_atomic_store(p, v, __ATOMIC_RELAXED, __HIP_MEMORY_SCOPE_AGENT);
}

__device__ __forceinline__ void tree_barrier(int* bar, int w, int epoch) {
  __syncthreads();
  if (threadIdx.x == 0) {
    const int g = w >> 3;
    int* gc = bar + g * 64;
    int* rc = bar + 2048;
    int* gf = bar + 2112 + g * 64;
    int old = __hip_atomic_fetch_add(gc, 1, __ATOMIC_RELAXED, __HIP_MEMORY_SCOPE_AGENT);
    if (old == epoch * 8 - 1) {
      __hip_atomic_fetch_add(rc, 1, __ATOMIC_RELAXED, __HIP_MEMORY_SCOPE_AGENT);
      while (__hip_atomic_load(rc, __ATOMIC_RELAXED, __HIP_MEMORY_SCOPE_AGENT) < epoch * 32)
        __builtin_amdgcn_s_sleep(2);
      __hip_atomic_store(gf, epoch, __ATOMIC_RELAXED, __HIP_MEMORY_SCOPE_AGENT);
    } else {
      while (__hip_atomic_load(gf, __ATOMIC_RELAXED, __HIP_MEMORY_SCOPE_AGENT) < epoch)
        __builtin_amdgcn_s_sleep(2);
    }
  }
  __syncthreads();
}

// ---------------------------------------------------------------------------
// Encoder: 256 WGs x 1024 thr. Thread (kk4, g, bp, ci): gate row g*512+col
// for batches bp and bp+16, k-quarter kk4 (64 floats per 256-chunk).
// Weights LDS-resident; x-phase (4 chunks), h-phase (2 chunks, pre-issued
// coherent loads) with fused enc_proj (g==0 threads, act-reads reused).
// ---------------------------------------------------------------------------
__global__ __launch_bounds__(1024) void encoder_kernel(
    const float* __restrict__ feats,
    const float* __restrict__ Wih_f, const float* __restrict__ Whh_f,
    const float* __restrict__ bih_f, const float* __restrict__ bhh_f,
    const float* __restrict__ Wih_b, const float* __restrict__ Whh_b,
    const float* __restrict__ bih_b, const float* __restrict__ bhh_b,
    const float* __restrict__ W_enc, const float* __restrict__ b_enc,
    float* __restrict__ enc_proj, float* __restrict__ henc,
    float* __restrict__ cfin, int* __restrict__ bar)
{
  extern __shared__ __align__(16) float dyn[];
  float* wih_l = dyn;            // 16 x 1028
  float* whh_l = dyn + 16448;    // 16 x 516
  __shared__ float hch[32 * 260];
  __shared__ float wenc[4 * 516];
  __shared__ float gpartK[4][32][17];
  __shared__ float projp[4][128];
  __shared__ float bias_s[16];
  __shared__ float benc_s[4];

  const int w = blockIdx.x;
  const int dir = (w >= 128) ? 1 : 0;
  const int wl = w & 127;
  const int col0 = wl * 4;
  const int t = threadIdx.x;
  const int kk4 = t >> 8;            // k-quarter 0..3
  const int u = t & 255;
  const int g = u >> 6;              // gate 0..3 (wave-uniform: bits 6..7)
  const int v = u & 63;
  const int bp = v >> 2;             // batches bp, bp+16
  const int ci = v & 3;
  // staging: 2 float4 positions per thread in [32][256] chunk
  const int p0b = t >> 6,          p0q = t & 63;
  const int p1b = (t + 1024) >> 6, p1q = (t + 1024) & 63;

  const float* Wih = dir ? Wih_b : Wih_f;
  const float* Whh = dir ? Whh_b : Whh_f;
  const float* bih = dir ? bih_b : bih_f;
  const float* bhh = dir ? bhh_b : bhh_f;

  for (int i = t; i < 16 * 256; i += 1024) {
    int r = i >> 8, q = i & 255;
    int gg = r >> 2, cj = r & 3;
    *(float4*)(wih_l + r * 1028 + q * 4) =
        *(const float4*)(Wih + (size_t)(gg * 512 + col0 + cj) * 1024 + q * 4);
  }
  for (int i = t; i < 16 * 128; i += 1024) {
    int r = i >> 7, q = i & 127;
    int gg = r >> 2, cj = r & 3;
    *(float4*)(whh_l + r * 516 + q * 4) =
        *(const float4*)(Whh + (size_t)(gg * 512 + col0 + cj) * 512 + q * 4);
  }
  for (int i = t; i < 4 * 128; i += 1024) {
    int jl = i >> 7, q = i & 127;
    *(float4*)(wenc + jl * 516 + q * 4) =
        *(const float4*)(W_enc + (size_t)(col0 + jl) * 1024 + dir * 512 + q * 4);
  }
  if (t < 16) {
    int gg = t >> 2, cj = t & 3;
    bias_s[t] = bih[gg * 512 + col0 + cj] + bhh[gg * 512 + col0 + cj];
  }
  if (t < 4) benc_s[t] = b_enc[col0 + t];
  float c_reg = 0.0f;
  __syncthreads();

  const float* wx = wih_l + (g * 4 + ci) * 1028;   // Wih row (g,ci)
  const float* wh = whh_l + (g * 4 + ci) * 516;    // Whh row (g,ci)
  const float* wpe = wenc + ci * 516;              // W_enc row (ci), g==0 use

  // prefetch feats chunk 0 for it=0
  const int s0_ = dir ? 511 : 0;
  float4 fx0 = *(const float4*)(feats + ((size_t)s0_ * 32) * 1024 + p0b * 1024 + p0q * 4);
  float4 fx1 = *(const float4*)(feats + ((size_t)s0_ * 32) * 1024 + p1b * 1024 + p1q * 4);

  for (int it = 0; it < 512; ++it) {
    const int s = dir ? (511 - it) : it;
    float acc0 = 0.0f, acc1 = 0.0f;
    float pacc0 = 0.0f, pacc1 = 0.0f;
    const float* fsrc = feats + ((size_t)s * 32) * 1024;
    const float* hsrc = henc + dir * 32768 + ((it - 1) & 1) * 16384;

    float2 h00a, h00b, h01a, h01b;
    float2 h10a, h10b, h11a, h11b;
    if (it > 0) {
      const float* sp;
      sp = hsrc + p0b * 512 + p0q * 4;       h00a = ldc2(sp); h00b = ldc2(sp + 2);
      sp = hsrc + p1b * 512 + p1q * 4;       h01a = ldc2(sp); h01b = ldc2(sp + 2);
      sp = hsrc + p0b * 512 + 256 + p0q * 4; h10a = ldc2(sp); h10b = ldc2(sp + 2);
      sp = hsrc + p1b * 512 + 256 + p1q * 4; h11a = ldc2(sp); h11b = ldc2(sp + 2);
    }

    // ---- x phase: 4 chunks of [32][256] ----
    {
      float4 xv0 = fx0;
      float4 xv1 = fx1;
      for (int ch = 0; ch < 4; ++ch) {
        *(float4*)(hch + p0b * 260 + p0q * 4) = xv0;
        *(float4*)(hch + p1b * 260 + p1q * 4) = xv1;
        __syncthreads();
        if (ch < 3) {
          xv0 = *(const float4*)(fsrc + p0b * 1024 + (ch + 1) * 256 + p0q * 4);
          xv1 = *(const float4*)(fsrc + p1b * 1024 + (ch + 1) * 256 + p1q * 4);
        }
        const float* aw = wx + ch * 256 + kk4 * 64;
        const float* h0 = hch + bp * 260 + kk4 * 64;
        const float* h1 = hch + (bp + 16) * 260 + kk4 * 64;
#pragma unroll 8
        for (int j = 0; j < 16; ++j) {
          float4 w4 = *(const float4*)(aw + j * 4);
          float4 a0 = *(const float4*)(h0 + j * 4);
          float4 a1 = *(const float4*)(h1 + j * 4);
          acc0 += w4.x * a0.x + w4.y * a0.y + w4.z * a0.z + w4.w * a0.w;
          acc1 += w4.x * a1.x + w4.y * a1.y + w4.z * a1.z + w4.w * a1.w;
        }
        __syncthreads();
      }
    }

    // ---- h phase: 2 chunks; proj fused (g==0, wave-uniform) ----
    if (it > 0) {
#pragma unroll
      for (int ch = 0; ch < 2; ++ch) {
        if (ch == 0) {
          *(float4*)(hch + p0b * 260 + p0q * 4) = make_float4(h00a.x, h00a.y, h00b.x, h00b.y);
          *(float4*)(hch + p1b * 260 + p1q * 4) = make_float4(h01a.x, h01a.y, h01b.x, h01b.y);
        } else {
          *(float4*)(hch + p0b * 260 + p0q * 4) = make_float4(h10a.x, h10a.y, h10b.x, h10b.y);
          *(float4*)(hch + p1b * 260 + p1q * 4) = make_float4(h11a.x, h11a.y, h11b.x, h11b.y);
        }
        __syncthreads();
        const float* aw = wh + ch * 256 + kk4 * 64;
        const float* h0 = hch + bp * 260 + kk4 * 64;
        const float* h1 = hch + (bp + 16) * 260 + kk4 * 64;
        if (g == 0) {
          const float* wp = wpe + ch * 256 + kk4 * 64;
#pragma unroll 4
          for (int j = 0; j < 16; ++j) {
            float4 w4 = *(const float4*)(aw + j * 4);
            float4 a0 = *(const float4*)(h0 + j * 4);
            float4 a1 = *(const float4*)(h1 + j * 4);
            float4 wp4 = *(const float4*)(wp + j * 4);
            acc0 += w4.x * a0.x + w4.y * a0.y + w4.z * a0.z + w4.w * a0.w;
            acc1 += w4.x * a1.x + w4.y * a1.y + w4.z * a1.z + w4.w * a1.w;
            pacc0 += wp4.x * a0.x + wp4.y * a0.y + wp4.z * a0.z + wp4.w * a0.w;
            pacc1 += wp4.x * a1.x + wp4.y * a1.y + wp4.z * a1.z + wp4.w * a1.w;
          }
        } else {
#pragma unroll 8
          for (int j = 0; j < 16; ++j) {
            float4 w4 = *(const float4*)(aw + j * 4);
            float4 a0 = *(const float4*)(h0 + j * 4);
            float4 a1 = *(const float4*)(h1 + j * 4);
            acc0 += w4.x * a0.x + w4.y * a0.y + w4.z * a0.z + w4.w * a0.w;
            acc1 += w4.x * a1.x + w4.y * a1.y + w4.z * a1.z + w4.w * a1.w;
          }
        }
        __syncthreads();
      }
    }

    gpartK[kk4][bp][g * 4 + ci] = acc0;
    gpartK[kk4][bp + 16][g * 4 + ci] = acc1;
    if (g == 0) {
      projp[kk4][bp * 4 + ci] = pacc0;
      projp[kk4][(bp + 16) * 4 + ci] = pacc1;
    }
    __syncthreads();
    if (t < 128) {
      const int b_ = t >> 2, ci_ = t & 3;
      float gi = gpartK[0][b_][ci_ + 0] + gpartK[1][b_][ci_ + 0] +
                 gpartK[2][b_][ci_ + 0] + gpartK[3][b_][ci_ + 0] + bias_s[ci_ + 0];
      float gf = gpartK[0][b_][ci_ + 4] + gpartK[1][b_][ci_ + 4] +
                 gpartK[2][b_][ci_ + 4] + gpartK[3][b_][ci_ + 4] + bias_s[ci_ + 4];
      float gg = gpartK[0][b_][ci_ + 8] + gpartK[1][b_][ci_ + 8] +
                 gpartK[2][b_][ci_ + 8] + gpartK[3][b_][ci_ + 8] + bias_s[ci_ + 8];
      float go = gpartK[0][b_][ci_ + 12] + gpartK[1][b_][ci_ + 12] +
                 gpartK[2][b_][ci_ + 12] + gpartK[3][b_][ci_ + 12] + bias_s[ci_ + 12];
      float cn = sigm(gf) * c_reg + sigm(gi) * tanhx(gg);
      c_reg = cn;
      stc(henc + dir * 32768 + (it & 1) * 16384 + b_ * 512 + col0 + ci_,
          sigm(go) * tanhx(cn));
    } else if (t >= 128 && t < 256 && it > 0) {
      const int l = t - 128, b_ = l >> 2, ci_ = l & 3;
      const int sp = dir ? (512 - it) : (it - 1);
      const float p = projp[0][l] + projp[1][l] + projp[2][l] + projp[3][l];
      float* addr = enc_proj + ((size_t)sp * 32 + b_) * 512 + col0 + ci_;
      if (it - 1 <= 255) {
        stc(addr, p + benc_s[ci_]);
      } else {
        stc(addr, ldc(addr) + p);
      }
    }
    // prefetch next step's feats chunk 0 (hidden under the barrier)
    {
      const int sn = (it < 511) ? (dir ? (510 - it) : (it + 1)) : s;
      const float* fn = feats + ((size_t)sn * 32) * 1024;
      fx0 = *(const float4*)(fn + p0b * 1024 + p0q * 4);
      fx1 = *(const float4*)(fn + p1b * 1024 + p1q * 4);
    }
    tree_barrier(bar, w, it + 1);
  }

  // post-loop: proj for e=511 (always second arriver), and cfin
  {
    const float* hsrc = henc + dir * 32768 + 16384;  // h[511] at pp=1
    float pacc0 = 0.0f, pacc1 = 0.0f;
    for (int ch = 0; ch < 2; ++ch) {
      for (int i = t; i < 2048; i += 1024) {   // 2048 float4s = [32][256]
        int bb = i >> 6, qf = i & 63;
        const float* sp = hsrc + bb * 512 + ch * 256 + qf * 4;
        float2 f0 = ldc2(sp);
        float2 f1 = ldc2(sp + 2);
        *(float4*)(hch + bb * 260 + qf * 4) = make_float4(f0.x, f0.y, f1.x, f1.y);
      }
      __syncthreads();
      if (g == 0) {
        const float* wp = wpe + ch * 256 + kk4 * 64;
        const float* h0 = hch + bp * 260 + kk4 * 64;
        const float* h1 = hch + (bp + 16) * 260 + kk4 * 64;
#pragma unroll 4
        for (int j = 0; j < 16; ++j) {
          float4 wp4 = *(const float4*)(wp + j * 4);
          float4 a0 = *(const float4*)(h0 + j * 4);
          float4 a1 = *(const float4*)(h1 + j * 4);
          pacc0 += wp4.x * a0.x + wp4.y * a0.y + wp4.z * a0.z + wp4.w * a0.w;
          pacc1 += wp4.x * a1.x + wp4.y * a1.y + wp4.z * a1.z + wp4.w * a1.w;
        }
      }
      __syncthreads();
    }
    if (g == 0) {
      projp[kk4][bp * 4 + ci] = pacc0;
      projp[kk4][(bp + 16) * 4 + ci] = pacc1;
    }
    __syncthreads();
    if (t >= 128 && t < 256) {
      const int l = t - 128, b_ = l >> 2, ci_ = l & 3;
      const int sp = dir ? 0 : 511;
      float* addr = enc_proj + ((size_t)sp * 32 + b_) * 512 + col0 + ci_;
      stc(addr, ldc(addr) + (projp[0][l] + projp[1][l] + projp[2][l] + projp[3][l]));
    }
    if (t < 128) cfin[dir * 16384 + (t >> 2) * 512 + col0 + (t & 3)] = c_reg;
  }
}

// ---------------------------------------------------------------------------
// Decoder: round-14 version verbatim (512 thr, 3 barriers/step, 2-deep
// register prefetch staging, phase C batch-major, phase D folded into A).
// ---------------------------------------------------------------------------
__global__ __launch_bounds__(512) void decoder_kernel(
    const float* __restrict__ feats,
    const float* __restrict__ Wih_d, const float* __restrict__ Whh_d,
    const float* __restrict__ bih_d, const float* __restrict__ bhh_d,
    const float* __restrict__ W_dec, const float* __restrict__ b_dec,
    const float* __restrict__ W_v, const float* __restrict__ b_v,
    const float* __restrict__ enc_proj, const float* __restrict__ henc,
    const float* __restrict__ cfin,
    float* __restrict__ hbuf, float* __restrict__ dproj,
    float* __restrict__ pval, int* __restrict__ pidx,
    int* __restrict__ bar, float* __restrict__ out)
{
  extern __shared__ __align__(16) float dyn[];
  float* whh_l = dyn;            // 16 x 1028
  float* wih_l = dyn + 16448;    // 16 x 1028
  __shared__ float hch[32 * 132];
  __shared__ float gpart[2][32][17];
  __shared__ float c_lds[32][4];
  __shared__ float bias_s[16];
  __shared__ float svals[64];
  __shared__ int ib_lds[32];
  float* dpl = hch + 1088;   // [8][68] dproj slice for phase C (alias)

  const int w = blockIdx.x;
  const int t = threadIdx.x;
  const int q4 = t >> 7;
  const int tt = t & 127;
  const int b = tt >> 2;
  const int ci = tt & 3;
  const int col0 = w * 4;
  const int col = col0 + ci;
  const int i0 = t, i1 = t + 512;
  const int bb0 = i0 >> 5, q0 = i0 & 31;
  const int bb1 = i1 >> 5, q1 = i1 & 31;
  const int bb_c = w >> 3;
  const int qq_ = w & 7;
  const int ccB = t >> 8;
  const int bB = (t >> 3) & 31;
  const int k8 = t & 7;

  for (int i = t; i < 16 * 256; i += 512) {
    int r = i >> 8, q = i & 255;
    int gg = r >> 2, cj = r & 3;
    *(float4*)(whh_l + r * 1028 + q * 4) =
        *(const float4*)(Whh_d + (size_t)(gg * 1024 + col0 + cj) * 1024 + q * 4);
    *(float4*)(wih_l + r * 1028 + q * 4) =
        *(const float4*)(Wih_d + (size_t)(gg * 1024 + col0 + cj) * 1024 + q * 4);
  }
  if (t < 16) {
    int gg = t >> 2, cj = t & 3;
    bias_s[t] = bih_d[gg * 1024 + col0 + cj] + bhh_d[gg * 1024 + col0 + cj];
  }
  if (t < 128) {
    int flat = b * 1024 + col;
    int d = flat >> 14, sb = (flat >> 9) & 31, sh = flat & 511;
    float h0, c0;
    if (d == 0) {
      h0 = henc[16384 + sb * 512 + sh];
      c0 = cfin[sb * 512 + sh];
    } else {
      h0 = henc[32768 + 16384 + sb * 512 + sh];
      c0 = cfin[16384 + sb * 512 + sh];
    }
    stc(hbuf + b * 1024 + col, h0);
    c_lds[b][ci] = c0;
  }
  int bars = 1;
  tree_barrier(bar, w, bars);

  const float* wbase = (q4 < 2) ? whh_l : wih_l;
  const int g0 = (q4 & 1) * 2;
  const float* wr0 = wbase + (size_t)((g0 + 0) * 4 + ci) * 1028;
  const float* wr1 = wbase + (size_t)((g0 + 1) * 4 + ci) * 1028;

  for (int ts = 0; ts < 128; ++ts) {
    const float* hprev = hbuf + (ts & 1) * 32768;
    float* hnext = hbuf + ((ts + 1) & 1) * 32768;

    // ---- phase A: gates GEMM (2-deep staged hprev) + cell; ib folded ----
    float a0 = 0.f, a1 = 0.f;
    const float* xrow = nullptr;
    {
      float2 s0a0 = ldc2(hprev + bb0 * 1024 + q0 * 4);
      float2 s0a1 = ldc2(hprev + bb0 * 1024 + q0 * 4 + 2);
      float2 s0b0 = ldc2(hprev + bb1 * 1024 + q1 * 4);
      float2 s0b1 = ldc2(hprev + bb1 * 1024 + q1 * 4 + 2);
      float2 s1a0 = ldc2(hprev + bb0 * 1024 + 128 + q0 * 4);
      float2 s1a1 = ldc2(hprev + bb0 * 1024 + 128 + q0 * 4 + 2);
      float2 s1b0 = ldc2(hprev + bb1 * 1024 + 128 + q1 * 4);
      float2 s1b1 = ldc2(hprev + bb1 * 1024 + 128 + q1 * 4 + 2);
      if (t < 32) {
        int ib = 0;
        if (ts > 0) {
          float v = ldc(pval + t * 8 + 0);
          int si = ldci(pidx + t * 8 + 0);
#pragma unroll
          for (int j = 1; j < 8; ++j) {
            float ov = ldc(pval + t * 8 + j);
            int os = ldci(pidx + t * 8 + j);
            if (ov > v || (ov == v && os < si)) { v = ov; si = os; }
          }
          ib = si;
        }
        ib_lds[t] = ib;
      }
      for (int ch = 0; ch < 8; ++ch) {
        if (ch & 1) {
          *(float4*)(hch + bb0 * 132 + q0 * 4) = make_float4(s1a0.x, s1a0.y, s1a1.x, s1a1.y);
          *(float4*)(hch + bb1 * 132 + q1 * 4) = make_float4(s1b0.x, s1b0.y, s1b1.x, s1b1.y);
        } else {
          *(float4*)(hch + bb0 * 132 + q0 * 4) = make_float4(s0a0.x, s0a0.y, s0a1.x, s0a1.y);
          *(float4*)(hch + bb1 * 132 + q1 * 4) = make_float4(s0b0.x, s0b0.y, s0b1.x, s0b1.y);
        }
        __syncthreads();
        if (ch == 0 && q4 >= 2) {
          int ib = ib_lds[b];
          xrow = feats + ((size_t)ib * 32 + b) * 1024;
        }
        if (ch < 6) {
          const int cn = (ch + 2) * 128;
          if (ch & 1) {
            s1a0 = ldc2(hprev + bb0 * 1024 + cn + q0 * 4);
            s1a1 = ldc2(hprev + bb0 * 1024 + cn + q0 * 4 + 2);
            s1b0 = ldc2(hprev + bb1 * 1024 + cn + q1 * 4);
            s1b1 = ldc2(hprev + bb1 * 1024 + cn + q1 * 4 + 2);
          } else {
            s0a0 = ldc2(hprev + bb0 * 1024 + cn + q0 * 4);
            s0a1 = ldc2(hprev + bb0 * 1024 + cn + q0 * 4 + 2);
            s0b0 = ldc2(hprev + bb1 * 1024 + cn + q1 * 4);
            s0b1 = ldc2(hprev + bb1 * 1024 + cn + q1 * 4 + 2);
          }
        }
        const float* src = (q4 < 2) ? (hch + b * 132) : (xrow + ch * 128);
        const float* p0 = wr0 + ch * 128;
        const float* p1 = wr1 + ch * 128;
#pragma unroll 8
        for (int qq = 0; qq < 32; ++qq) {
          float4 h4 = *(const float4*)(src + qq * 4);
          float4 u0 = *(const float4*)(p0 + qq * 4);
          float4 u1 = *(const float4*)(p1 + qq * 4);
          a0 += h4.x * u0.x + h4.y * u0.y + h4.z * u0.z + h4.w * u0.w;
          a1 += h4.x * u1.x + h4.y * u1.y + h4.z * u1.z + h4.w * u1.w;
        }
        __syncthreads();
      }
    }
    gpart[q4 >> 1][b][ci + (g0 + 0) * 4] = a0;
    gpart[q4 >> 1][b][ci + (g0 + 1) * 4] = a1;
    __syncthreads();
    if (t < 128) {
      float gi = gpart[0][b][ci + 0] + gpart[1][b][ci + 0] + bias_s[ci + 0];
      float gf = gpart[0][b][ci + 4] + gpart[1][b][ci + 4] + bias_s[ci + 4];
      float gg = gpart[0][b][ci + 8] + gpart[1][b][ci + 8] + bias_s[ci + 8];
      float go = gpart[0][b][ci + 12] + gpart[1][b][ci + 12] + bias_s[ci + 12];
      float cn = sigm(gf) * c_lds[b][ci] + sigm(gi) * tanhx(gg);
      c_lds[b][ci] = cn;
      stc(hnext + b * 1024 + col, sigm(go) * tanhx(cn));
    }
    ++bars; tree_barrier(bar, w, bars);

    // ---- phase B: dproj cols {2w,2w+1}; hnext 2-deep staged, 8-way k-split --
    {
      float dacc = 0.f;
      const float* wdrow = W_dec + (size_t)(2 * w + ccB) * 1024;
      float2 s0a0 = ldc2(hnext + bb0 * 1024 + q0 * 4);
      float2 s0a1 = ldc2(hnext + bb0 * 1024 + q0 * 4 + 2);
      float2 s0b0 = ldc2(hnext + bb1 * 1024 + q1 * 4);
      float2 s0b1 = ldc2(hnext + bb1 * 1024 + q1 * 4 + 2);
      float2 s1a0 = ldc2(hnext + bb0 * 1024 + 128 + q0 * 4);
      float2 s1a1 = ldc2(hnext + bb0 * 1024 + 128 + q0 * 4 + 2);
      float2 s1b0 = ldc2(hnext + bb1 * 1024 + 128 + q1 * 4);
      float2 s1b1 = ldc2(hnext + bb1 * 1024 + 128 + q1 * 4 + 2);
      for (int ch = 0; ch < 8; ++ch) {
        if (ch & 1) {
          *(float4*)(hch + bb0 * 132 + q0 * 4) = make_float4(s1a0.x, s1a0.y, s1a1.x, s1a1.y);
          *(float4*)(hch + bb1 * 132 + q1 * 4) = make_float4(s1b0.x, s1b0.y, s1b1.x, s1b1.y);
        } else {
          *(float4*)(hch + bb0 * 132 + q0 * 4) = make_float4(s0a0.x, s0a0.y, s0a1.x, s0a1.y);
          *(float4*)(hch + bb1 * 132 + q1 * 4) = make_float4(s0b0.x, s0b0.y, s0b1.x, s0b1.y);
        }
        __syncthreads();
        if (ch < 6) {
          const int cn = (ch + 2) * 128;
          if (ch & 1) {
            s1a0 = ldc2(hnext + bb0 * 1024 + cn + q0 * 4);
            s1a1 = ldc2(hnext + bb0 * 1024 + cn + q0 * 4 + 2);
            s1b0 = ldc2(hnext + bb1 * 1024 + cn + q1 * 4);
            s1b1 = ldc2(hnext + bb1 * 1024 + cn + q1 * 4 + 2);
          } else {
            s0a0 = ldc2(hnext + bb0 * 1024 + cn + q0 * 4);
            s0a1 = ldc2(hnext + bb0 * 1024 + cn + q0 * 4 + 2);
            s0b0 = ldc2(hnext + bb1 * 1024 + cn + q1 * 4);
            s0b1 = ldc2(hnext + bb1 * 1024 + cn + q1 * 4 + 2);
          }
        }
        const float* hl = hch + bB * 132 + k8 * 16;
        const float* wl = wdrow + ch * 128 + k8 * 16;
#pragma unroll
        for (int j = 0; j < 4; ++j) {
          float4 h4 = *(const float4*)(hl + j * 4);
          float4 w4 = *(const float4*)(wl + j * 4);
          dacc += h4.x * w4.x + h4.y * w4.y + h4.z * w4.z + h4.w * w4.w;
        }
        __syncthreads();
      }
      dacc += __shfl_xor(dacc, 1);
      dacc += __shfl_xor(dacc, 2);
      dacc += __shfl_xor(dacc, 4);
      if (k8 == 0) stc(dproj + bB * 512 + 2 * w + ccB, dacc + b_dec[2 * w + ccB]);
    }
    ++bars; tree_barrier(bar, w, bars);

    // ---- phase C: scores, batch-major (WG: bb_c, s-block qq_) ----
    if (t < 256) {
      float2 v = ldc2(dproj + bb_c * 512 + 2 * t);
      int k = 2 * t;
      dpl[(k >> 6) * 68 + (k & 63) + 0] = v.x;
      dpl[(k >> 6) * 68 + (k & 63) + 1] = v.y;
    }
    __syncthreads();
    {
      const int sl = t >> 3, ks = t & 7;
      const int s = qq_ * 64 + sl;
      const float* ep = enc_proj + ((size_t)s * 32 + bb_c) * 512 + ks * 64;
      const float* dpp = dpl + ks * 68;
      const float* wvp = W_v + ks * 64;
      float sum = 0.f;
#pragma unroll 4
      for (int j = 0; j < 16; ++j) {
        float4 e4 = *(const float4*)(ep + j * 4);
        float4 d4 = *(const float4*)(dpp + j * 4);
        float4 v4 = *(const float4*)(wvp + j * 4);
        sum += tanhx(e4.x + d4.x) * v4.x;
        sum += tanhx(e4.y + d4.y) * v4.y;
        sum += tanhx(e4.z + d4.z) * v4.z;
        sum += tanhx(e4.w + d4.w) * v4.w;
      }
      sum += __shfl_xor(sum, 1);
      sum += __shfl_xor(sum, 2);
      sum += __shfl_xor(sum, 4);
      if (ks == 0) {
        float sv = sum + b_v[0];
        out[((size_t)ts * 32 + bb_c) * 512 + s] = sv;
        svals[sl] = sv;
      }
    }
    __syncthreads();
    if (t < 64) {
      float v = svals[t];
      int si = qq_ * 64 + t;
#pragma unroll
      for (int m = 1; m < 64; m <<= 1) {
        float ov = __shfl_xor(v, m);
        int os = __shfl_xor(si, m);
        if (ov > v || (ov == v && os < si)) { v = ov; si = os; }
      }
      if (t == 0) {
        stc(pval + bb_c * 8 + qq_, v);
        stci(pidx + bb_c * 8 + qq_, si);
      }
    }
    ++bars; tree_barrier(bar, w, bars);
  }
}

// ---------------------------------------------------------------------------
extern "C" void kernel_launch(void* const* d_in, const int* in_sizes, int n_in,
                              void* d_out, int out_size, void* d_ws, size_t ws_size,
                              hipStream_t stream) {
  (void)in_sizes; (void)n_in; (void)out_size; (void)ws_size;
  const float* feats = (const float*)d_in[0];
  const float* Wih_f = (const float*)d_in[1];
  const float* Whh_f = (const float*)d_in[2];
  const float* bih_f = (const float*)d_in[3];
  const float* bhh_f = (const float*)d_in[4];
  const float* Wih_b = (const float*)d_in[5];
  const float* Whh_b = (const float*)d_in[6];
  const float* bih_b = (const float*)d_in[7];
  const float* bhh_b = (const float*)d_in[8];
  const float* Wih_d = (const float*)d_in[9];
  const float* Whh_d = (const float*)d_in[10];
  const float* bih_d = (const float*)d_in[11];
  const float* bhh_d = (const float*)d_in[12];
  const float* W_enc = (const float*)d_in[13];
  const float* b_enc = (const float*)d_in[14];
  const float* W_dec = (const float*)d_in[15];
  const float* b_dec = (const float*)d_in[16];
  const float* W_v   = (const float*)d_in[17];
  const float* b_v   = (const float*)d_in[18];
  float* out = (float*)d_out;

  int* ctrl = (int*)d_ws;
  int* bar_enc = ctrl;
  int* bar_dec = ctrl + 8192;
  float* base = (float*)d_ws + 16384;        // after 64 KiB ctrl block
  float* enc_proj = base;                    // 8,388,608
  float* henc     = enc_proj + 8388608;      //    65,536
  float* cfin     = henc + 65536;            //    32,768
  float* hbuf     = cfin + 32768;            //    65,536
  float* dproj    = hbuf + 65536;            //    16,384
  float* pval     = dproj + 16384;           //     8,192 (256 used)
  int*   pidx     = (int*)(pval + 8192);     //     8,192 (256 used)
  // total ~34.4 MB

  const int ENC_LDS = (16 * 1028 + 16 * 516) * 4;   //  98,816 B
  const int DEC_LDS = (2 * 16 * 1028) * 4;          // 131,584 B
  hipFuncSetAttribute((const void*)encoder_kernel,
                      hipFuncAttributeMaxDynamicSharedMemorySize, ENC_LDS);
  hipFuncSetAttribute((const void*)decoder_kernel,
                      hipFuncAttributeMaxDynamicSharedMemorySize, DEC_LDS);

  hipMemsetAsync(d_ws, 0, 65536, stream);

  {
    void* args[] = {(void*)&feats,
                    (void*)&Wih_f, (void*)&Whh_f, (void*)&bih_f, (void*)&bhh_f,
                    (void*)&Wih_b, (void*)&Whh_b, (void*)&bih_b, (void*)&bhh_b,
                    (void*)&W_enc, (void*)&b_enc,
                    (void*)&enc_proj, (void*)&henc, (void*)&cfin, (void*)&bar_enc};
    hipLaunchCooperativeKernel((const void*)encoder_kernel, dim3(NWG), dim3(1024),
                               args, ENC_LDS, stream);
  }
  {
    void* args[] = {(void*)&feats,
                    (void*)&Wih_d, (void*)&Whh_d, (void*)&bih_d, (void*)&bhh_d,
                    (void*)&W_dec, (void*)&b_dec, (void*)&W_v, (void*)&b_v,
                    (void*)&enc_proj, (void*)&henc, (void*)&cfin,
                    (void*)&hbuf, (void*)&dproj, (void*)&pval, (void*)&pidx,
                    (void*)&bar_dec, (void*)&out};
    hipLaunchCooperativeKernel((const void*)decoder_kernel, dim3(NWG), dim3(512),
                               args, DEC_LDS, stream);
  }
}